// Round 3
// baseline (298.584 us; speedup 1.0000x reference)
//
#include <hip/hip_runtime.h>

typedef __bf16 bf16x8 __attribute__((ext_vector_type(8)));
typedef float f32x4 __attribute__((ext_vector_type(4)));
typedef float f32x16 __attribute__((ext_vector_type(16)));

__device__ inline ushort f2bf(float f) {
    unsigned u = __builtin_bit_cast(unsigned, f);
    unsigned r = (u + 0x7FFFu + ((u >> 16) & 1u)) >> 16;  // RNE
    return (ushort)r;
}
__device__ inline float bf2f(ushort u) {
    unsigned x = ((unsigned)u) << 16;
    return __builtin_bit_cast(float, x);
}
__device__ inline uint4 pack8(const float* f) {
    uint4 r;
    r.x = (unsigned)f2bf(f[0]) | ((unsigned)f2bf(f[1]) << 16);
    r.y = (unsigned)f2bf(f[2]) | ((unsigned)f2bf(f[3]) << 16);
    r.z = (unsigned)f2bf(f[4]) | ((unsigned)f2bf(f[5]) << 16);
    r.w = (unsigned)f2bf(f[6]) | ((unsigned)f2bf(f[7]) << 16);
    return r;
}
__device__ inline unsigned cvtpk_bf16(float lo, float hi) {
    unsigned r;
    asm("v_cvt_pk_bf16_f32 %0, %1, %2" : "=v"(r) : "v"(lo), "v"(hi));
    return r;
}

#define MFMA_BF16(a, b, c) __builtin_amdgcn_mfma_f32_16x16x32_bf16(a, b, c, 0, 0, 0)
#define MFMA32(a, b, c) __builtin_amdgcn_mfma_f32_32x32x16_bf16(a, b, c, 0, 0, 0)
#define GLDS(g, l) __builtin_amdgcn_global_load_lds( \
    (const __attribute__((address_space(1))) void*)(g), \
    (__attribute__((address_space(3))) void*)(l), 16, 0, 0)

// Q pre-scaled by 1/sqrt(64)*log2(e): scores land in exp2 domain.
#define QSCALE 0.18033688011112042f

// Convert fp32 x / qkv_w / proj_w to bf16. 8 elems/thread, 4096x256.
__global__ __launch_bounds__(256) void convert3(
    const float* __restrict__ s0, ushort* __restrict__ d0,
    const float* __restrict__ s1, ushort* __restrict__ d1,
    const float* __restrict__ s2, ushort* __restrict__ d2)
{
    const int i = blockIdx.x * 256 + threadIdx.x;
    const float* s; ushort* d; int off;
    if (i < 524288)      { s = s0; d = d0; off = i; }
    else if (i < 917504) { s = s1; d = d1; off = i - 524288; }
    else                 { s = s2; d = d2; off = i - 917504; }
    const float4* f = (const float4*)s + off * 2;
    float fa[8];
    *(float4*)&fa[0] = f[0];
    *(float4*)&fa[4] = f[1];
    ((uint4*)d)[off] = pack8(fa);
}

// QKV = x @ qkv_w^T + bias. 128x128 tile, BK=64, global_load_lds, XOR-swizzled LDS.
// 2-phase prefetch + XCD-chunked block remap. (unchanged)
__global__ __launch_bounds__(256) void gemm_qkv(
    const ushort* __restrict__ A, const ushort* __restrict__ B,
    const float* __restrict__ bias,
    ushort* __restrict__ outQ, ushort* __restrict__ outK, ushort* __restrict__ outV,
    int N, int K)
{
    __shared__ __align__(16) ushort SMEM[32768];  // 64 KB: 2 x (As 16KB + Bs 16KB)

    const int tid = threadIdx.x;
    const int w = tid >> 6;
    const int lane = tid & 63;
    const int l15 = lane & 15;
    const int quad = lane >> 4;
    const int srow = lane >> 3;

    const int bid = blockIdx.x + (blockIdx.y << 5);       // grid (32, 24), x fastest
    const int nb = (bid & 7) * 96 + (bid >> 3);           // bijective, 768 % 8 == 0
    const int m0 = (nb / 24) * 128;
    const int n0 = (nb % 24) * 128;
    const int wr = (w & 1) * 64;
    const int wc = (w >> 1) * 64;

    auto stage = [&](int k0, int buf) {
        ushort* As = SMEM + buf * 16384;
        ushort* Bs = As + 8192;
#pragma unroll
        for (int j = 0; j < 4; j++) {
            const int r0 = w * 32 + j * 8;
            const int row = r0 + srow;
            const int gcol = ((lane & 7) ^ (row & 7)) * 8;   // pre-swizzled source
            GLDS(A + (size_t)(m0 + row) * K + k0 + gcol, As + r0 * 64);
            GLDS(B + (size_t)(n0 + row) * K + k0 + gcol, Bs + r0 * 64);
        }
    };

    f32x4 acc[4][4] = {};

    stage(0, 0);
    __syncthreads();   // implicit vmcnt(0): buf0 landed

    for (int k0 = 0; k0 < K; k0 += 64) {
        const int cur = (k0 >> 6) & 1;
        if (k0 + 64 < K) stage(k0 + 64, cur ^ 1);   // overlaps frag-load + MFMA below

        const ushort* As = SMEM + cur * 16384;
        const ushort* Bs = As + 8192;
        bf16x8 af[4][2], bf[4][2];
#pragma unroll
        for (int i = 0; i < 4; i++)
#pragma unroll
            for (int kk = 0; kk < 2; kk++) {
                const int ra = wr + i * 16 + l15;
                const int rb = wc + i * 16 + l15;
                af[i][kk] = *(const bf16x8*)&As[ra * 64 + (((kk * 4 + quad) ^ (ra & 7)) * 8)];
                bf[i][kk] = *(const bf16x8*)&Bs[rb * 64 + (((kk * 4 + quad) ^ (rb & 7)) * 8)];
            }
#pragma unroll
        for (int kk = 0; kk < 2; kk++)
#pragma unroll
            for (int mi = 0; mi < 4; mi++)
#pragma unroll
                for (int ni = 0; ni < 4; ni++)
                    acc[mi][ni] = MFMA_BF16(af[mi][kk], bf[ni][kk], acc[mi][ni]);
        __syncthreads();   // one barrier per K-step; drains prefetch + ds_reads
    }

    const int which = n0 >> 10;            // 0=Q 1=K 2=V
    ushort* Ct = SMEM;                     // 128 x 136 (safe: loop ended on barrier)
    if (which == 2) {
#pragma unroll
        for (int mi = 0; mi < 4; mi++)
#pragma unroll
            for (int ni = 0; ni < 4; ni++)
#pragma unroll
                for (int r = 0; r < 4; r++) {
                    const int m_loc = wr + mi * 16 + quad * 4 + r;
                    const int n_loc = wc + ni * 16 + l15;
                    Ct[n_loc * 136 + m_loc] =
                        f2bf(acc[mi][ni][r] + bias[n0 + n_loc]);
                }
        __syncthreads();
        const int b = m0 >> 11;
#pragma unroll
        for (int i = 0; i < 8; i++) {
            const int vi = tid + i * 256;
            const int n_loc = vi >> 4, mblk = vi & 15;
            const uint4 val = *(const uint4*)&Ct[n_loc * 136 + mblk * 8];
            const int t = (m0 & 2047) + mblk * 8;
            const int c = (n0 + n_loc) & 1023;
            const int h = c >> 6, d = c & 63;
            *(uint4*)&outV[((size_t)(b * 16 + h) * 64 + d) * 2048 + t] = val;
        }
    } else {
        const float qs = (which == 0) ? QSCALE : 1.0f;
#pragma unroll
        for (int mi = 0; mi < 4; mi++)
#pragma unroll
            for (int ni = 0; ni < 4; ni++)
#pragma unroll
                for (int r = 0; r < 4; r++) {
                    const int m_loc = wr + mi * 16 + quad * 4 + r;
                    const int n_loc = wc + ni * 16 + l15;
                    Ct[m_loc * 136 + n_loc] =
                        f2bf((acc[mi][ni][r] + bias[n0 + n_loc]) * qs);
                }
        __syncthreads();
        ushort* outP = (which == 0) ? outQ : outK;
        const int hb = (n0 & 1023) >> 6;
        const int b = m0 >> 11;
#pragma unroll
        for (int i = 0; i < 8; i++) {
            const int vi = tid + i * 256;
            const int m_loc = vi >> 4, u = vi & 15;
            const uint4 val = *(const uint4*)&Ct[m_loc * 136 + u * 8];
            const int t = (m0 & 2047) + m_loc;
            const int h = hb + (u >> 3);
            const int d8 = (u & 7) * 8;
            *(uint4*)&outP[((size_t)(b * 16 + h)) * 131072 + (size_t)t * 64 + d8] = val;
        }
    }
}

// proj: out = O @ proj_w^T + bias (fp32). 64x128 tile -> 512 blocks (2/CU).
// (unchanged)
__global__ __launch_bounds__(256) void gemm_proj(
    const ushort* __restrict__ A, const ushort* __restrict__ B,
    const float* __restrict__ bias, float* __restrict__ outD)
{
    const int N = 1024, K = 1024;
    __shared__ __align__(16) ushort SMEM[24576];  // 48 KB: 2 x (As 8KB + Bs 16KB)

    const int tid = threadIdx.x;
    const int w = tid >> 6;
    const int lane = tid & 63;
    const int l15 = lane & 15;
    const int quad = lane >> 4;
    const int srow = lane >> 3;

    const int bid = blockIdx.x + (blockIdx.y << 6);       // grid (64, 8), x fastest
    const int nb = (bid & 7) * 64 + (bid >> 3);           // bijective, 512 % 8 == 0
    const int m0 = (nb >> 3) * 64;                        // XCD k: m-tiles [8k,8k+8)
    const int n0 = (nb & 7) * 128;
    const int wr = (w & 1) * 32;
    const int wc = (w >> 1) * 64;

    auto stage = [&](int k0, int buf) {
        ushort* As = SMEM + buf * 12288;
        ushort* Bs = As + 4096;
#pragma unroll
        for (int j = 0; j < 2; j++) {
            const int r0 = w * 16 + j * 8;
            const int row = r0 + srow;
            const int gcol = ((lane & 7) ^ (row & 7)) * 8;
            GLDS(A + (size_t)(m0 + row) * K + k0 + gcol, As + r0 * 64);
        }
#pragma unroll
        for (int j = 0; j < 4; j++) {
            const int r0 = w * 32 + j * 8;
            const int row = r0 + srow;
            const int gcol = ((lane & 7) ^ (row & 7)) * 8;
            GLDS(B + (size_t)(n0 + row) * K + k0 + gcol, Bs + r0 * 64);
        }
    };

    f32x4 acc[2][4] = {};

    stage(0, 0);
    __syncthreads();

    for (int k0 = 0; k0 < K; k0 += 64) {
        const int cur = (k0 >> 6) & 1;
        if (k0 + 64 < K) stage(k0 + 64, cur ^ 1);

        const ushort* As = SMEM + cur * 12288;
        const ushort* Bs = As + 4096;
        bf16x8 af[2][2], bf[4][2];
#pragma unroll
        for (int kk = 0; kk < 2; kk++) {
#pragma unroll
            for (int mi = 0; mi < 2; mi++) {
                const int ra = wr + mi * 16 + l15;
                af[mi][kk] = *(const bf16x8*)&As[ra * 64 + (((kk * 4 + quad) ^ (ra & 7)) * 8)];
            }
#pragma unroll
            for (int ni = 0; ni < 4; ni++) {
                const int rb = wc + ni * 16 + l15;
                bf[ni][kk] = *(const bf16x8*)&Bs[rb * 64 + (((kk * 4 + quad) ^ (rb & 7)) * 8)];
            }
        }
#pragma unroll
        for (int kk = 0; kk < 2; kk++)
#pragma unroll
            for (int mi = 0; mi < 2; mi++)
#pragma unroll
                for (int ni = 0; ni < 4; ni++)
                    acc[mi][ni] = MFMA_BF16(af[mi][kk], bf[ni][kk], acc[mi][ni]);
        __syncthreads();
    }

    float* Cf = (float*)SMEM;                      // 64 x 68 floats
#pragma unroll
    for (int cch = 0; cch < 2; cch++) {
        __syncthreads();
        if ((wc >> 6) == cch) {
#pragma unroll
            for (int mi = 0; mi < 2; mi++)
#pragma unroll
                for (int ni = 0; ni < 4; ni++)
#pragma unroll
                    for (int r = 0; r < 4; r++) {
                        const int m_loc = wr + mi * 16 + quad * 4 + r;
                        const int nl = ni * 16 + l15;
                        Cf[m_loc * 68 + nl] = acc[mi][ni][r] + bias[n0 + cch * 64 + nl];
                    }
        }
        __syncthreads();
#pragma unroll
        for (int i = 0; i < 4; i++) {
            const int vi = tid + i * 256;
            const int m_loc = vi >> 4, u = vi & 15;
            const float4 val = *(const float4*)&Cf[m_loc * 68 + u * 4];
            *(float4*)&outD[(size_t)(m0 + m_loc) * N + n0 + cch * 64 + u * 4] = val;
        }
    }
}

// Split-K flash attention, static softmax (kt tiles are independent pure sums).
// 32x32 MFMA, swapped QK^T, in-register softmax (exp2 -> cvt_pk -> permlane32).
// 4 waves x 32 q-rows = 128-row Q tiles, KV tiles 64, double-buffered (32 KB LDS,
// 5 blocks/CU). Balanced split-K: qt0-3 direct; qt4-7 x2; qt8-11 x3; qt12-15 x4
// chunks (5-8 tiles each) -> grid (32, 40) = 1280 blocks = exactly 5/CU.
// Epilogue repacks O through the idle KV buffer half -> coalesced 16B stores.
__global__ __launch_bounds__(256, 5) void attn_split(
    const ushort* __restrict__ Q, const ushort* __restrict__ K,
    const ushort* __restrict__ Vt, ushort* __restrict__ O,
    ushort* __restrict__ Opart, float* __restrict__ Lpart)
{
    __shared__ __align__(16) ushort KV[2][2][64 * 64];  // 32 KB

    // XCD-chunked remap: XCD k owns bh in [4k, 4k+4), all 40 y each.
    const int bid0 = blockIdx.x + blockIdx.y * 32;      // 0..1279
    const int nb = (bid0 & 7) * 160 + (bid0 >> 3);      // bijective, 1280 % 8 == 0
    const int bh = (nb / 160) * 4 + (nb % 160) / 40;
    const int y = nb % 40;

    int qt, k0, k1, split;
    const int slot = y - 4;
    if (y < 4) {
        qt = y; k0 = 0; k1 = 2 * qt + 2; split = 0;
    } else {
        split = 1;
        const int z = y - 4;
        int ci, c;
        if (z < 8)       { qt = 4 + (z >> 1); ci = z & 1; c = 2; }
        else if (z < 20) { const int t = z - 8;  qt = 8 + t / 3;   ci = t % 3; c = 3; }
        else             { const int t = z - 20; qt = 12 + (t >> 2); ci = t & 3; c = 4; }
        const int n = 2 * qt + 2;
        k0 = ci * n / c;
        k1 = (ci + 1) * n / c;
    }
    const int q0 = qt * 128;
    const int tid = threadIdx.x;
    const int w = tid >> 6;
    const int lane = tid & 63;
    const int l31 = lane & 31;
    const int hf = lane >> 5;
    const int wrow0 = q0 + w * 32;             // wave's first q-row
    const int rowg = wrow0 + l31;              // lane's q-row

    auto stage = [&](int kt, int b) {
        const int t0 = kt * 64;
#pragma unroll
        for (int j = 0; j < 2; j++) {
            const int r0 = w * 16 + j * 8;
            const int row = r0 + (lane >> 3);
            const int gcol = ((lane & 7) ^ (row & 7)) * 8;
            GLDS(K + ((size_t)bh * 2048 + t0 + row) * 64 + gcol, &KV[b][0][r0 * 64]);
            GLDS(Vt + ((size_t)bh * 64 + row) * 2048 + t0 + gcol, &KV[b][1][r0 * 64]);
        }
    };

    // Q fragments (B-operand of S^T MFMA): lane holds q-col = rowg
    const ushort* qbase = Q + ((size_t)bh * 2048 + rowg) * 64 + hf * 8;
    bf16x8 qf[4];
#pragma unroll
    for (int db = 0; db < 4; db++) qf[db] = *(const bf16x8*)(qbase + db * 16);

    bf16x8 ones;
#pragma unroll
    for (int j = 0; j < 8; j++) ones[j] = (__bf16)1.0f;

    f32x16 oacc[2] = {};
    f32x16 lacc = {};

    stage(k0, 0);

    for (int kt = k0; kt < k1; kt++) {
        __syncthreads();
        if (kt + 1 < k1) stage(kt + 1, (kt + 1 - k0) & 1);

        const ushort* Ks = &KV[(kt - k0) & 1][0][0];
        const ushort* Vs = &KV[(kt - k0) & 1][1][0];
        const int t0 = kt * 64;

        if (t0 <= wrow0 + 31) {                 // wave not fully masked
            // S^T = K · Q^T : A = K rows (k), B = Q cols (q)
            f32x16 sacc[2] = {};
#pragma unroll
            for (int db = 0; db < 4; db++)
#pragma unroll
                for (int kb = 0; kb < 2; kb++) {
                    const int rr = kb * 32 + l31;
                    bf16x8 kf = *(const bf16x8*)&Ks[rr * 64 + (((db * 2 + hf) ^ (rr & 7)) * 8)];
                    sacc[kb] = MFMA32(kf, qf[db], sacc[kb]);
                }

            // exp2 + pack pairs (k adjacent within reg-pairs)
            unsigned u[2][8];
            const bool nm = (t0 + 63 > wrow0);  // diagonal tile for this wave
#pragma unroll
            for (int kb = 0; kb < 2; kb++) {
                float p[16];
                if (nm) {
#pragma unroll
                    for (int reg = 0; reg < 16; reg++) {
                        const int col = t0 + kb * 32 + (reg & 3) + 8 * (reg >> 2) + 4 * hf;
                        float x = (col > rowg) ? -1e30f : sacc[kb][reg];
                        p[reg] = __builtin_exp2f(x);
                    }
                } else {
#pragma unroll
                    for (int reg = 0; reg < 16; reg++)
                        p[reg] = __builtin_exp2f(sacc[kb][reg]);
                }
#pragma unroll
                for (int t = 0; t < 8; t++)
                    u[kb][t] = cvtpk_bf16(p[2 * t], p[2 * t + 1]);
            }

            // half-wave 2x2 block transpose: after these, af[m] = u[m>>1][(m&1)*4 ..+3]
#pragma unroll
            for (int kb = 0; kb < 2; kb++)
#pragma unroll
                for (int g = 0; g < 4; g++) {
                    const int tp = (g & 1) + (g >> 1) * 4;
                    asm("v_permlane32_swap_b32 %0, %1"
                        : "+v"(u[kb][tp]), "+v"(u[kb][tp + 2]));
                }

            // PV + row-sums
#pragma unroll
            for (int m = 0; m < 4; m++) {
                uint4 av;
                av.x = u[m >> 1][(m & 1) * 4 + 0];
                av.y = u[m >> 1][(m & 1) * 4 + 1];
                av.z = u[m >> 1][(m & 1) * 4 + 2];
                av.w = u[m >> 1][(m & 1) * 4 + 3];
                bf16x8 af = __builtin_bit_cast(bf16x8, av);
                lacc = MFMA32(af, ones, lacc);
#pragma unroll
                for (int d2 = 0; d2 < 2; d2++) {
                    const int rr = d2 * 32 + l31;
                    bf16x8 vf = *(const bf16x8*)&Vs[rr * 64 + (((m * 2 + hf) ^ (rr & 7)) * 8)];
                    oacc[d2] = MFMA32(af, vf, oacc[d2]);
                }
            }
        }
    }

    // ---- epilogue: repack through the KV buffer half the final tile doesn't read.
    // All waves are past the final top-barrier, so only buffer (k1-1-k0)&1 is being
    // read; we write (k1-k0)&1. No staging targets it (last iter skips stage).
    ushort* Ob = &KV[(k1 - k0) & 1][0][0];     // 16 KB = 128 rows x 64 cols bf16
    if (split) {
        if (l31 == 0) {
            const size_t slot2 = (size_t)bh * 36 + slot;
#pragma unroll
            for (int reg = 0; reg < 16; reg++)
                Lpart[slot2 * 128 + w * 32 + (reg & 3) + 8 * (reg >> 2) + 4 * hf] = lacc[reg];
        }
#pragma unroll
        for (int reg = 0; reg < 16; reg++) {
            const int rl = w * 32 + (reg & 3) + 8 * (reg >> 2) + 4 * hf;
#pragma unroll
            for (int d2 = 0; d2 < 2; d2++)
                Ob[rl * 64 + d2 * 32 + l31] = f2bf(oacc[d2][reg]);
        }
    } else {
#pragma unroll
        for (int reg = 0; reg < 16; reg++) {
            const float inv = 1.0f / lacc[reg];
            const int rl = w * 32 + (reg & 3) + 8 * (reg >> 2) + 4 * hf;
#pragma unroll
            for (int d2 = 0; d2 < 2; d2++)
                Ob[rl * 64 + d2 * 32 + l31] = f2bf(oacc[d2][reg] * inv);
        }
    }
    __syncthreads();
    if (split) {
        const size_t slot2 = (size_t)bh * 36 + slot;
        ushort* dst = Opart + slot2 * 8192;
#pragma unroll
        for (int i = 0; i < 4; i++) {
            const int idx = tid + i * 256;
            *(uint4*)&dst[idx * 8] = *(const uint4*)&Ob[idx * 8];
        }
    } else {
        const int b = bh >> 4, hh = bh & 15;
#pragma unroll
        for (int i = 0; i < 4; i++) {
            const int idx = tid + i * 256;
            const int rl = idx >> 3, c0 = (idx & 7) * 8;
            *(uint4*)&O[((size_t)b * 2048 + q0 + rl) * 1024 + hh * 64 + c0] =
                *(const uint4*)&Ob[idx * 8];
        }
    }
}

// Combine: O[bh, qt 4..15] = sum(partials) / sum(l). grid (32, 12), 128-row slots.
// c = (qt>>2)+1 partials per qt.
__global__ __launch_bounds__(256) void attn_combine(
    const ushort* __restrict__ Opart, const float* __restrict__ Lpart,
    ushort* __restrict__ O)
{
    const int bh = blockIdx.x;
    const int qt = 4 + blockIdx.y;           // 4..15
    const int c = (qt >> 2) + 1;             // 2,3,4
    int base;
    if (qt < 8)       base = (qt - 4) * 2;
    else if (qt < 12) base = 8 + (qt - 8) * 3;
    else              base = 20 + (qt - 12) * 4;
    const int tid = threadIdx.x;
    const int row = tid >> 1;                // 0..127
    const int dg = (tid & 1) * 32;           // d half
    const size_t s = (size_t)bh * 36 + base;
    float lsum = 0.f;
    for (int j = 0; j < c; j++) lsum += Lpart[(s + j) * 128 + row];
    const float inv = 1.0f / lsum;
    const int b = bh >> 4, hh = bh & 15;
    ushort* dst = O + ((size_t)b * 2048 + qt * 128 + row) * 1024 + hh * 64 + dg;
#pragma unroll
    for (int v = 0; v < 4; v++) {
        float accf[8] = {};
        for (int j = 0; j < c; j++) {
            uint4 a = *(const uint4*)(Opart + (s + j) * 8192 + row * 64 + dg + v * 8);
            const ushort* ua = (const ushort*)&a;
#pragma unroll
            for (int t = 0; t < 8; t++) accf[t] += bf2f(ua[t]);
        }
        ushort out[8];
#pragma unroll
        for (int t = 0; t < 8; t++) out[t] = f2bf(accf[t] * inv);
        *(uint4*)(dst + v * 8) = *(uint4*)out;
    }
}

extern "C" void kernel_launch(void* const* d_in, const int* in_sizes, int n_in,
                              void* d_out, int out_size, void* d_ws, size_t ws_size,
                              hipStream_t stream) {
    const float* x      = (const float*)d_in[0];
    const float* qkv_w  = (const float*)d_in[1];
    const float* qkv_b  = (const float*)d_in[2];
    const float* proj_w = (const float*)d_in[3];
    const float* proj_b = (const float*)d_in[4];

    // Workspace (55.1 MB total, within proven footprint). Wqkv region is dead
    // after gemm_qkv and is reused for Opart/Lpart during attention.
    ushort* XbOb  = (ushort*)d_ws + 16;      // [4096,1024] bf16; reused for attn O
    ushort* Wproj = XbOb + 4194304;          // 1,048,576
    ushort* Qb    = Wproj + 1048576;         // [32,2048,64]
    ushort* Kb    = Qb + 4194304;
    ushort* Vt    = Kb + 4194304;            // [32,64,2048]
    ushort* Wqkv  = Vt + 4194304;            // 3,145,728 (dead after gemm_qkv)
    ushort* Opart = Wqkv;                    // [32][36][128*64] bf16 = 18.9 MB
    float*  Lpart = (float*)(Opart + 9437184);  // [32][36][128] fp32

    convert3<<<4096, 256, 0, stream>>>(x, XbOb, qkv_w, Wqkv, proj_w, Wproj);
    gemm_qkv<<<dim3(32, 24), 256, 0, stream>>>(XbOb, Wqkv, qkv_b,
                                               Qb, Kb, Vt, 3072, 1024);
    attn_split<<<dim3(32, 40), 256, 0, stream>>>(Qb, Kb, Vt, XbOb, Opart, Lpart);
    attn_combine<<<dim3(32, 12), 256, 0, stream>>>(Opart, Lpart, XbOb);
    gemm_proj<<<dim3(64, 8), 256, 0, stream>>>(XbOb, Wproj, proj_b, (float*)d_out);
}

// Round 4
// 204.286 us; speedup vs baseline: 1.4616x; 1.4616x over previous
//
#include <hip/hip_runtime.h>

typedef __bf16 bf16x8 __attribute__((ext_vector_type(8)));
typedef float f32x4 __attribute__((ext_vector_type(4)));
typedef float f32x16 __attribute__((ext_vector_type(16)));

__device__ inline ushort f2bf(float f) {
    unsigned u = __builtin_bit_cast(unsigned, f);
    unsigned r = (u + 0x7FFFu + ((u >> 16) & 1u)) >> 16;  // RNE
    return (ushort)r;
}
__device__ inline float bf2f(ushort u) {
    unsigned x = ((unsigned)u) << 16;
    return __builtin_bit_cast(float, x);
}
__device__ inline uint4 pack8(const float* f) {
    uint4 r;
    r.x = (unsigned)f2bf(f[0]) | ((unsigned)f2bf(f[1]) << 16);
    r.y = (unsigned)f2bf(f[2]) | ((unsigned)f2bf(f[3]) << 16);
    r.z = (unsigned)f2bf(f[4]) | ((unsigned)f2bf(f[5]) << 16);
    r.w = (unsigned)f2bf(f[6]) | ((unsigned)f2bf(f[7]) << 16);
    return r;
}
__device__ inline unsigned cvtpk_bf16(float lo, float hi) {
    unsigned r;
    asm("v_cvt_pk_bf16_f32 %0, %1, %2" : "=v"(r) : "v"(lo), "v"(hi));
    return r;
}

#define MFMA_BF16(a, b, c) __builtin_amdgcn_mfma_f32_16x16x32_bf16(a, b, c, 0, 0, 0)
#define MFMA32(a, b, c) __builtin_amdgcn_mfma_f32_32x32x16_bf16(a, b, c, 0, 0, 0)
#define GLDS(g, l) __builtin_amdgcn_global_load_lds( \
    (const __attribute__((address_space(1))) void*)(g), \
    (__attribute__((address_space(3))) void*)(l), 16, 0, 0)

// Q pre-scaled by 1/sqrt(64)*log2(e): scores land in exp2 domain.
#define QSCALE 0.18033688011112042f

// Convert fp32 x / qkv_w / proj_w to bf16. 8 elems/thread, 4096x256.
__global__ __launch_bounds__(256) void convert3(
    const float* __restrict__ s0, ushort* __restrict__ d0,
    const float* __restrict__ s1, ushort* __restrict__ d1,
    const float* __restrict__ s2, ushort* __restrict__ d2)
{
    const int i = blockIdx.x * 256 + threadIdx.x;
    const float* s; ushort* d; int off;
    if (i < 524288)      { s = s0; d = d0; off = i; }
    else if (i < 917504) { s = s1; d = d1; off = i - 524288; }
    else                 { s = s2; d = d2; off = i - 917504; }
    const float4* f = (const float4*)s + off * 2;
    float fa[8];
    *(float4*)&fa[0] = f[0];
    *(float4*)&fa[4] = f[1];
    ((uint4*)d)[off] = pack8(fa);
}

// QKV = x @ qkv_w^T + bias. 128x128 tile, BK=64, global_load_lds, XOR-swizzled LDS.
// 2-phase prefetch + XCD-chunked block remap. (unchanged)
__global__ __launch_bounds__(256) void gemm_qkv(
    const ushort* __restrict__ A, const ushort* __restrict__ B,
    const float* __restrict__ bias,
    ushort* __restrict__ outQ, ushort* __restrict__ outK, ushort* __restrict__ outV,
    int N, int K)
{
    __shared__ __align__(16) ushort SMEM[32768];  // 64 KB: 2 x (As 16KB + Bs 16KB)

    const int tid = threadIdx.x;
    const int w = tid >> 6;
    const int lane = tid & 63;
    const int l15 = lane & 15;
    const int quad = lane >> 4;
    const int srow = lane >> 3;

    const int bid = blockIdx.x + (blockIdx.y << 5);       // grid (32, 24), x fastest
    const int nb = (bid & 7) * 96 + (bid >> 3);           // bijective, 768 % 8 == 0
    const int m0 = (nb / 24) * 128;
    const int n0 = (nb % 24) * 128;
    const int wr = (w & 1) * 64;
    const int wc = (w >> 1) * 64;

    auto stage = [&](int k0, int buf) {
        ushort* As = SMEM + buf * 16384;
        ushort* Bs = As + 8192;
#pragma unroll
        for (int j = 0; j < 4; j++) {
            const int r0 = w * 32 + j * 8;
            const int row = r0 + srow;
            const int gcol = ((lane & 7) ^ (row & 7)) * 8;   // pre-swizzled source
            GLDS(A + (size_t)(m0 + row) * K + k0 + gcol, As + r0 * 64);
            GLDS(B + (size_t)(n0 + row) * K + k0 + gcol, Bs + r0 * 64);
        }
    };

    f32x4 acc[4][4] = {};

    stage(0, 0);
    __syncthreads();   // implicit vmcnt(0): buf0 landed

    for (int k0 = 0; k0 < K; k0 += 64) {
        const int cur = (k0 >> 6) & 1;
        if (k0 + 64 < K) stage(k0 + 64, cur ^ 1);   // overlaps frag-load + MFMA below

        const ushort* As = SMEM + cur * 16384;
        const ushort* Bs = As + 8192;
        bf16x8 af[4][2], bf[4][2];
#pragma unroll
        for (int i = 0; i < 4; i++)
#pragma unroll
            for (int kk = 0; kk < 2; kk++) {
                const int ra = wr + i * 16 + l15;
                const int rb = wc + i * 16 + l15;
                af[i][kk] = *(const bf16x8*)&As[ra * 64 + (((kk * 4 + quad) ^ (ra & 7)) * 8)];
                bf[i][kk] = *(const bf16x8*)&Bs[rb * 64 + (((kk * 4 + quad) ^ (rb & 7)) * 8)];
            }
#pragma unroll
        for (int kk = 0; kk < 2; kk++)
#pragma unroll
            for (int mi = 0; mi < 4; mi++)
#pragma unroll
                for (int ni = 0; ni < 4; ni++)
                    acc[mi][ni] = MFMA_BF16(af[mi][kk], bf[ni][kk], acc[mi][ni]);
        __syncthreads();   // one barrier per K-step; drains prefetch + ds_reads
    }

    const int which = n0 >> 10;            // 0=Q 1=K 2=V
    ushort* Ct = SMEM;                     // 128 x 136 (safe: loop ended on barrier)
    if (which == 2) {
#pragma unroll
        for (int mi = 0; mi < 4; mi++)
#pragma unroll
            for (int ni = 0; ni < 4; ni++)
#pragma unroll
                for (int r = 0; r < 4; r++) {
                    const int m_loc = wr + mi * 16 + quad * 4 + r;
                    const int n_loc = wc + ni * 16 + l15;
                    Ct[n_loc * 136 + m_loc] =
                        f2bf(acc[mi][ni][r] + bias[n0 + n_loc]);
                }
        __syncthreads();
        const int b = m0 >> 11;
#pragma unroll
        for (int i = 0; i < 8; i++) {
            const int vi = tid + i * 256;
            const int n_loc = vi >> 4, mblk = vi & 15;
            const uint4 val = *(const uint4*)&Ct[n_loc * 136 + mblk * 8];
            const int t = (m0 & 2047) + mblk * 8;
            const int c = (n0 + n_loc) & 1023;
            const int h = c >> 6, d = c & 63;
            *(uint4*)&outV[((size_t)(b * 16 + h) * 64 + d) * 2048 + t] = val;
        }
    } else {
        const float qs = (which == 0) ? QSCALE : 1.0f;
#pragma unroll
        for (int mi = 0; mi < 4; mi++)
#pragma unroll
            for (int ni = 0; ni < 4; ni++)
#pragma unroll
                for (int r = 0; r < 4; r++) {
                    const int m_loc = wr + mi * 16 + quad * 4 + r;
                    const int n_loc = wc + ni * 16 + l15;
                    Ct[m_loc * 136 + n_loc] =
                        f2bf((acc[mi][ni][r] + bias[n0 + n_loc]) * qs);
                }
        __syncthreads();
        ushort* outP = (which == 0) ? outQ : outK;
        const int hb = (n0 & 1023) >> 6;
        const int b = m0 >> 11;
#pragma unroll
        for (int i = 0; i < 8; i++) {
            const int vi = tid + i * 256;
            const int m_loc = vi >> 4, u = vi & 15;
            const uint4 val = *(const uint4*)&Ct[m_loc * 136 + u * 8];
            const int t = (m0 & 2047) + m_loc;
            const int h = hb + (u >> 3);
            const int d8 = (u & 7) * 8;
            *(uint4*)&outP[((size_t)(b * 16 + h)) * 131072 + (size_t)t * 64 + d8] = val;
        }
    }
}

// proj: out = O @ proj_w^T + bias (fp32). 64x128 tile -> 512 blocks (2/CU).
// (unchanged)
__global__ __launch_bounds__(256) void gemm_proj(
    const ushort* __restrict__ A, const ushort* __restrict__ B,
    const float* __restrict__ bias, float* __restrict__ outD)
{
    const int N = 1024, K = 1024;
    __shared__ __align__(16) ushort SMEM[24576];  // 48 KB: 2 x (As 8KB + Bs 16KB)

    const int tid = threadIdx.x;
    const int w = tid >> 6;
    const int lane = tid & 63;
    const int l15 = lane & 15;
    const int quad = lane >> 4;
    const int srow = lane >> 3;

    const int bid = blockIdx.x + (blockIdx.y << 6);       // grid (64, 8), x fastest
    const int nb = (bid & 7) * 64 + (bid >> 3);           // bijective, 512 % 8 == 0
    const int m0 = (nb >> 3) * 64;                        // XCD k: m-tiles [8k,8k+8)
    const int n0 = (nb & 7) * 128;
    const int wr = (w & 1) * 32;
    const int wc = (w >> 1) * 64;

    auto stage = [&](int k0, int buf) {
        ushort* As = SMEM + buf * 12288;
        ushort* Bs = As + 4096;
#pragma unroll
        for (int j = 0; j < 2; j++) {
            const int r0 = w * 16 + j * 8;
            const int row = r0 + srow;
            const int gcol = ((lane & 7) ^ (row & 7)) * 8;
            GLDS(A + (size_t)(m0 + row) * K + k0 + gcol, As + r0 * 64);
        }
#pragma unroll
        for (int j = 0; j < 4; j++) {
            const int r0 = w * 32 + j * 8;
            const int row = r0 + srow;
            const int gcol = ((lane & 7) ^ (row & 7)) * 8;
            GLDS(B + (size_t)(n0 + row) * K + k0 + gcol, Bs + r0 * 64);
        }
    };

    f32x4 acc[2][4] = {};

    stage(0, 0);
    __syncthreads();

    for (int k0 = 0; k0 < K; k0 += 64) {
        const int cur = (k0 >> 6) & 1;
        if (k0 + 64 < K) stage(k0 + 64, cur ^ 1);

        const ushort* As = SMEM + cur * 12288;
        const ushort* Bs = As + 4096;
        bf16x8 af[2][2], bf[4][2];
#pragma unroll
        for (int kk = 0; kk < 2; kk++) {
#pragma unroll
            for (int mi = 0; mi < 2; mi++) {
                const int ra = wr + mi * 16 + l15;
                af[mi][kk] = *(const bf16x8*)&As[ra * 64 + (((kk * 4 + quad) ^ (ra & 7)) * 8)];
            }
#pragma unroll
            for (int ni = 0; ni < 4; ni++) {
                const int rb = wc + ni * 16 + l15;
                bf[ni][kk] = *(const bf16x8*)&Bs[rb * 64 + (((kk * 4 + quad) ^ (rb & 7)) * 8)];
            }
        }
#pragma unroll
        for (int kk = 0; kk < 2; kk++)
#pragma unroll
            for (int mi = 0; mi < 2; mi++)
#pragma unroll
                for (int ni = 0; ni < 4; ni++)
                    acc[mi][ni] = MFMA_BF16(af[mi][kk], bf[ni][kk], acc[mi][ni]);
        __syncthreads();
    }

    float* Cf = (float*)SMEM;                      // 64 x 68 floats
#pragma unroll
    for (int cch = 0; cch < 2; cch++) {
        __syncthreads();
        if ((wc >> 6) == cch) {
#pragma unroll
            for (int mi = 0; mi < 2; mi++)
#pragma unroll
                for (int ni = 0; ni < 4; ni++)
#pragma unroll
                    for (int r = 0; r < 4; r++) {
                        const int m_loc = wr + mi * 16 + quad * 4 + r;
                        const int nl = ni * 16 + l15;
                        Cf[m_loc * 68 + nl] = acc[mi][ni][r] + bias[n0 + cch * 64 + nl];
                    }
        }
        __syncthreads();
#pragma unroll
        for (int i = 0; i < 4; i++) {
            const int vi = tid + i * 256;
            const int m_loc = vi >> 4, u = vi & 15;
            const float4 val = *(const float4*)&Cf[m_loc * 68 + u * 4];
            *(float4*)&outD[(size_t)(m0 + m_loc) * N + n0 + cch * 64 + u * 4] = val;
        }
    }
}

// Split-K flash attention, static softmax (kt tiles are independent pure sums).
// 32x32 MFMA, swapped QK^T, in-register softmax (exp2 -> cvt_pk -> permlane32).
// 4 waves x 32 q-rows = 128-row Q tiles, KV tiles 64, double-buffered (32 KB LDS).
// Balanced split-K: qt0-3 direct; qt4-7 x2; qt8-11 x3; qt12-15 x4 chunks
// (5-8 tiles each) -> grid (32, 40) = 1280 blocks.
// __launch_bounds__(256,4): 128 reg/wave budget -- (256,5) forced VGPR=48 and
// spilled the ~112-reg live set to scratch (round 3: 0.5 GB HBM traffic, 152us).
// Epilogue repacks O through the idle KV buffer half -> coalesced 16B stores.
__global__ __launch_bounds__(256, 4) void attn_split(
    const ushort* __restrict__ Q, const ushort* __restrict__ K,
    const ushort* __restrict__ Vt, ushort* __restrict__ O,
    ushort* __restrict__ Opart, float* __restrict__ Lpart)
{
    __shared__ __align__(16) ushort KV[2][2][64 * 64];  // 32 KB

    // XCD-chunked remap: XCD k owns bh in [4k, 4k+4), all 40 y each.
    const int bid0 = blockIdx.x + blockIdx.y * 32;      // 0..1279
    const int nb = (bid0 & 7) * 160 + (bid0 >> 3);      // bijective, 1280 % 8 == 0
    const int bh = (nb / 160) * 4 + (nb % 160) / 40;
    const int y = nb % 40;

    int qt, k0, k1, split;
    const int slot = y - 4;
    if (y < 4) {
        qt = y; k0 = 0; k1 = 2 * qt + 2; split = 0;
    } else {
        split = 1;
        const int z = y - 4;
        int ci, c;
        if (z < 8)       { qt = 4 + (z >> 1); ci = z & 1; c = 2; }
        else if (z < 20) { const int t = z - 8;  qt = 8 + t / 3;   ci = t % 3; c = 3; }
        else             { const int t = z - 20; qt = 12 + (t >> 2); ci = t & 3; c = 4; }
        const int n = 2 * qt + 2;
        k0 = ci * n / c;
        k1 = (ci + 1) * n / c;
    }
    const int q0 = qt * 128;
    const int tid = threadIdx.x;
    const int w = tid >> 6;
    const int lane = tid & 63;
    const int l31 = lane & 31;
    const int hf = lane >> 5;
    const int wrow0 = q0 + w * 32;             // wave's first q-row
    const int rowg = wrow0 + l31;              // lane's q-row

    auto stage = [&](int kt, int b) {
        const int t0 = kt * 64;
#pragma unroll
        for (int j = 0; j < 2; j++) {
            const int r0 = w * 16 + j * 8;
            const int row = r0 + (lane >> 3);
            const int gcol = ((lane & 7) ^ (row & 7)) * 8;
            GLDS(K + ((size_t)bh * 2048 + t0 + row) * 64 + gcol, &KV[b][0][r0 * 64]);
            GLDS(Vt + ((size_t)bh * 64 + row) * 2048 + t0 + gcol, &KV[b][1][r0 * 64]);
        }
    };

    // Q fragments (B-operand of S^T MFMA): lane holds q-col = rowg
    const ushort* qbase = Q + ((size_t)bh * 2048 + rowg) * 64 + hf * 8;
    bf16x8 qf[4];
#pragma unroll
    for (int db = 0; db < 4; db++) qf[db] = *(const bf16x8*)(qbase + db * 16);

    bf16x8 ones;
#pragma unroll
    for (int j = 0; j < 8; j++) ones[j] = (__bf16)1.0f;

    f32x16 oacc[2] = {};
    f32x16 lacc = {};

    stage(k0, 0);

    for (int kt = k0; kt < k1; kt++) {
        __syncthreads();
        if (kt + 1 < k1) stage(kt + 1, (kt + 1 - k0) & 1);

        const ushort* Ks = &KV[(kt - k0) & 1][0][0];
        const ushort* Vs = &KV[(kt - k0) & 1][1][0];
        const int t0 = kt * 64;

        if (t0 <= wrow0 + 31) {                 // wave not fully masked
            // S^T = K · Q^T : A = K rows (k), B = Q cols (q)
            f32x16 sacc[2] = {};
#pragma unroll
            for (int db = 0; db < 4; db++)
#pragma unroll
                for (int kb = 0; kb < 2; kb++) {
                    const int rr = kb * 32 + l31;
                    bf16x8 kf = *(const bf16x8*)&Ks[rr * 64 + (((db * 2 + hf) ^ (rr & 7)) * 8)];
                    sacc[kb] = MFMA32(kf, qf[db], sacc[kb]);
                }

            // exp2 + pack pairs (k adjacent within reg-pairs)
            unsigned u[2][8];
            const bool nm = (t0 + 63 > wrow0);  // diagonal tile for this wave
#pragma unroll
            for (int kb = 0; kb < 2; kb++) {
                float p[16];
                if (nm) {
#pragma unroll
                    for (int reg = 0; reg < 16; reg++) {
                        const int col = t0 + kb * 32 + (reg & 3) + 8 * (reg >> 2) + 4 * hf;
                        float x = (col > rowg) ? -1e30f : sacc[kb][reg];
                        p[reg] = __builtin_exp2f(x);
                    }
                } else {
#pragma unroll
                    for (int reg = 0; reg < 16; reg++)
                        p[reg] = __builtin_exp2f(sacc[kb][reg]);
                }
#pragma unroll
                for (int t = 0; t < 8; t++)
                    u[kb][t] = cvtpk_bf16(p[2 * t], p[2 * t + 1]);
            }

            // half-wave 2x2 block transpose: after these, af[m] = u[m>>1][(m&1)*4 ..+3]
#pragma unroll
            for (int kb = 0; kb < 2; kb++)
#pragma unroll
                for (int g = 0; g < 4; g++) {
                    const int tp = (g & 1) + (g >> 1) * 4;
                    asm("v_permlane32_swap_b32 %0, %1"
                        : "+v"(u[kb][tp]), "+v"(u[kb][tp + 2]));
                }

            // PV + row-sums
#pragma unroll
            for (int m = 0; m < 4; m++) {
                uint4 av;
                av.x = u[m >> 1][(m & 1) * 4 + 0];
                av.y = u[m >> 1][(m & 1) * 4 + 1];
                av.z = u[m >> 1][(m & 1) * 4 + 2];
                av.w = u[m >> 1][(m & 1) * 4 + 3];
                bf16x8 af = __builtin_bit_cast(bf16x8, av);
                lacc = MFMA32(af, ones, lacc);
#pragma unroll
                for (int d2 = 0; d2 < 2; d2++) {
                    const int rr = d2 * 32 + l31;
                    bf16x8 vf = *(const bf16x8*)&Vs[rr * 64 + (((m * 2 + hf) ^ (rr & 7)) * 8)];
                    oacc[d2] = MFMA32(af, vf, oacc[d2]);
                }
            }
        }
    }

    // ---- epilogue: repack through the KV buffer half the final tile doesn't read.
    // All waves are past the final top-barrier, so only buffer (k1-1-k0)&1 is being
    // read; we write (k1-k0)&1. No staging targets it (last iter skips stage).
    ushort* Ob = &KV[(k1 - k0) & 1][0][0];     // 16 KB = 128 rows x 64 cols bf16
    if (split) {
        if (l31 == 0) {
            const size_t slot2 = (size_t)bh * 36 + slot;
#pragma unroll
            for (int reg = 0; reg < 16; reg++)
                Lpart[slot2 * 128 + w * 32 + (reg & 3) + 8 * (reg >> 2) + 4 * hf] = lacc[reg];
        }
#pragma unroll
        for (int reg = 0; reg < 16; reg++) {
            const int rl = w * 32 + (reg & 3) + 8 * (reg >> 2) + 4 * hf;
#pragma unroll
            for (int d2 = 0; d2 < 2; d2++)
                Ob[rl * 64 + d2 * 32 + l31] = f2bf(oacc[d2][reg]);
        }
    } else {
#pragma unroll
        for (int reg = 0; reg < 16; reg++) {
            const float inv = 1.0f / lacc[reg];
            const int rl = w * 32 + (reg & 3) + 8 * (reg >> 2) + 4 * hf;
#pragma unroll
            for (int d2 = 0; d2 < 2; d2++)
                Ob[rl * 64 + d2 * 32 + l31] = f2bf(oacc[d2][reg] * inv);
        }
    }
    __syncthreads();
    if (split) {
        const size_t slot2 = (size_t)bh * 36 + slot;
        ushort* dst = Opart + slot2 * 8192;
#pragma unroll
        for (int i = 0; i < 4; i++) {
            const int idx = tid + i * 256;
            *(uint4*)&dst[idx * 8] = *(const uint4*)&Ob[idx * 8];
        }
    } else {
        const int b = bh >> 4, hh = bh & 15;
#pragma unroll
        for (int i = 0; i < 4; i++) {
            const int idx = tid + i * 256;
            const int rl = idx >> 3, c0 = (idx & 7) * 8;
            *(uint4*)&O[((size_t)b * 2048 + q0 + rl) * 1024 + hh * 64 + c0] =
                *(const uint4*)&Ob[idx * 8];
        }
    }
}

// Combine: O[bh, qt 4..15] = sum(partials) / sum(l). grid (32, 12), 128-row slots.
// c = (qt>>2)+1 partials per qt.
__global__ __launch_bounds__(256) void attn_combine(
    const ushort* __restrict__ Opart, const float* __restrict__ Lpart,
    ushort* __restrict__ O)
{
    const int bh = blockIdx.x;
    const int qt = 4 + blockIdx.y;           // 4..15
    const int c = (qt >> 2) + 1;             // 2,3,4
    int base;
    if (qt < 8)       base = (qt - 4) * 2;
    else if (qt < 12) base = 8 + (qt - 8) * 3;
    else              base = 20 + (qt - 12) * 4;
    const int tid = threadIdx.x;
    const int row = tid >> 1;                // 0..127
    const int dg = (tid & 1) * 32;           // d half
    const size_t s = (size_t)bh * 36 + base;
    float lsum = 0.f;
    for (int j = 0; j < c; j++) lsum += Lpart[(s + j) * 128 + row];
    const float inv = 1.0f / lsum;
    const int b = bh >> 4, hh = bh & 15;
    ushort* dst = O + ((size_t)b * 2048 + qt * 128 + row) * 1024 + hh * 64 + dg;
#pragma unroll
    for (int v = 0; v < 4; v++) {
        float accf[8] = {};
        for (int j = 0; j < c; j++) {
            uint4 a = *(const uint4*)(Opart + (s + j) * 8192 + row * 64 + dg + v * 8);
            const ushort* ua = (const ushort*)&a;
#pragma unroll
            for (int t = 0; t < 8; t++) accf[t] += bf2f(ua[t]);
        }
        ushort out[8];
#pragma unroll
        for (int t = 0; t < 8; t++) out[t] = f2bf(accf[t] * inv);
        *(uint4*)(dst + v * 8) = *(uint4*)out;
    }
}

extern "C" void kernel_launch(void* const* d_in, const int* in_sizes, int n_in,
                              void* d_out, int out_size, void* d_ws, size_t ws_size,
                              hipStream_t stream) {
    const float* x      = (const float*)d_in[0];
    const float* qkv_w  = (const float*)d_in[1];
    const float* qkv_b  = (const float*)d_in[2];
    const float* proj_w = (const float*)d_in[3];
    const float* proj_b = (const float*)d_in[4];

    // Workspace (55.1 MB total, within proven footprint). Wqkv region is dead
    // after gemm_qkv and is reused for Opart/Lpart during attention.
    ushort* XbOb  = (ushort*)d_ws + 16;      // [4096,1024] bf16; reused for attn O
    ushort* Wproj = XbOb + 4194304;          // 1,048,576
    ushort* Qb    = Wproj + 1048576;         // [32,2048,64]
    ushort* Kb    = Qb + 4194304;
    ushort* Vt    = Kb + 4194304;            // [32,64,2048]
    ushort* Wqkv  = Vt + 4194304;            // 3,145,728 (dead after gemm_qkv)
    ushort* Opart = Wqkv;                    // [32][36][128*64] bf16 = 18.9 MB
    float*  Lpart = (float*)(Opart + 9437184);  // [32][36][128] fp32

    convert3<<<4096, 256, 0, stream>>>(x, XbOb, qkv_w, Wqkv, proj_w, Wproj);
    gemm_qkv<<<dim3(32, 24), 256, 0, stream>>>(XbOb, Wqkv, qkv_b,
                                               Qb, Kb, Vt, 3072, 1024);
    attn_split<<<dim3(32, 40), 256, 0, stream>>>(Qb, Kb, Vt, XbOb, Opart, Lpart);
    attn_combine<<<dim3(32, 12), 256, 0, stream>>>(Opart, Lpart, XbOb);
    gemm_proj<<<dim3(64, 8), 256, 0, stream>>>(XbOb, Wproj, proj_b, (float*)d_out);
}